// Round 7
// baseline (2199.602 us; speedup 1.0000x reference)
//
#include <hip/hip_runtime.h>

typedef __bf16 bf16x8 __attribute__((ext_vector_type(8)));
typedef float f32x4 __attribute__((ext_vector_type(4)));
typedef unsigned short us8 __attribute__((ext_vector_type(8)));
typedef unsigned short us4 __attribute__((ext_vector_type(4)));

__device__ __forceinline__ unsigned short f2bf(float f) {
  unsigned u = __builtin_bit_cast(unsigned, f);
  u += 0x7FFFu + ((u >> 16) & 1u);
  return (unsigned short)(u >> 16);
}
__device__ __forceinline__ float bf2f(unsigned short h) {
  return __builtin_bit_cast(float, (unsigned)h << 16);
}
__device__ __forceinline__ void glds16(const void* g, void* l) {
  __builtin_amdgcn_global_load_lds(
      (__attribute__((address_space(1))) void*)g,
      (__attribute__((address_space(3))) void*)l, 16, 0, 0);
}

// ---------------- fp32 -> bf16 conversion (vectorized, grid-stride) --------
__global__ __launch_bounds__(256) void cvt_bf16(const float* __restrict__ in,
                                                unsigned short* __restrict__ out,
                                                long n8) {
  const long stride = (long)gridDim.x * 256;
  for (long c = (long)blockIdx.x * 256 + threadIdx.x; c < n8; c += stride) {
    const float4 a = ((const float4*)in)[c * 2];
    const float4 b = ((const float4*)in)[c * 2 + 1];
    us8 u;
    u[0] = f2bf(a.x); u[1] = f2bf(a.y); u[2] = f2bf(a.z); u[3] = f2bf(a.w);
    u[4] = f2bf(b.x); u[5] = f2bf(b.y); u[6] = f2bf(b.z); u[7] = f2bf(b.w);
    ((us8*)out)[c] = u;
  }
}

// ---------------- RMSNorm: fp32 row -> bf16 row ----------------------------
__global__ __launch_bounds__(256) void rmsnorm_k(const float* __restrict__ x,
                                                 const float* __restrict__ wgt,
                                                 unsigned short* __restrict__ out) {
  const int r = blockIdx.x, t = threadIdx.x;
  const float* xr = x + (long)r * 4096;
  float4 vv[4];
  float ss = 0.f;
#pragma unroll
  for (int i = 0; i < 4; ++i) {
    float4 v = ((const float4*)xr)[t + i * 256];
    vv[i] = v;
    ss += v.x * v.x + v.y * v.y + v.z * v.z + v.w * v.w;
  }
#pragma unroll
  for (int off = 1; off < 64; off <<= 1) ss += __shfl_xor(ss, off);
  __shared__ float ps[4];
  if ((t & 63) == 0) ps[t >> 6] = ss;
  __syncthreads();
  ss = ps[0] + ps[1] + ps[2] + ps[3];
  const float rinv = rsqrtf(ss * (1.f / 4096.f) + 1e-5f);
#pragma unroll
  for (int i = 0; i < 4; ++i) {
    const int c4 = t + i * 256;
    const float4 v = vv[i];
    const float4 g = ((const float4*)wgt)[c4];
    us4 u;
    u[0] = f2bf(v.x * rinv * g.x);
    u[1] = f2bf(v.y * rinv * g.y);
    u[2] = f2bf(v.z * rinv * g.z);
    u[3] = f2bf(v.w * rinv * g.w);
    *(us4*)(out + (long)r * 4096 + c4 * 4) = u;
  }
}

// ---------------- bf16 NT GEMM: C = A(MxK) * B(NxK)^T, m97 structure -------
// LDS[row][c] = G[row][c ^ (row&7)] in 16B chunks (linear dest for
// global_load_lds, inverse-swizzled source, swizzled read — rule #21).
// MODE 0: fp32 out = acc + bias[col]
// MODE 1: fp32 out = acc + extra[row*N+col]        (residual add)
// MODE 2: bf16 out = acc
// MODE 3: bf16 out = acc + bias[col]
// MODE 4: bf16 out = silu(extra_bf16[row*N+col]) * acc   (fused SwiGLU;
//         in-place over extra is safe: read idx == write idx per thread)
template <int MODE>
__global__ __launch_bounds__(256)
void gemm_nt(const unsigned short* __restrict__ A,
             const unsigned short* __restrict__ B,
             void* __restrict__ outp, const void* __restrict__ extra,
             int M, int N, int K) {
  __shared__ unsigned short lsA[128 * 64];
  __shared__ unsigned short lsB[128 * 64];
  const int t = threadIdx.x;
  const int l = t & 63, w = t >> 6;
  const int fr = l & 15, fq = l >> 4;
  const int wr = w >> 1, wc = w & 1;
  const int bm0 = blockIdx.x * 128, bn0 = blockIdx.y * 128;
  const int stgrow = w * 8 + (l >> 3);
  const int stgch = (l & 7) ^ (l >> 3);

  f32x4 acc[4][4] = {};

  for (int k0 = 0; k0 < K; k0 += 64) {
#pragma unroll
    for (int i = 0; i < 4; ++i) {
      glds16(A + (long)(bm0 + i * 32 + stgrow) * K + k0 + stgch * 8,
             (char*)lsA + i * 4096 + w * 1024);
      glds16(B + (long)(bn0 + i * 32 + stgrow) * K + k0 + stgch * 8,
             (char*)lsB + i * 4096 + w * 1024);
    }
    __syncthreads();
#pragma unroll
    for (int kk = 0; kk < 2; ++kk) {
      bf16x8 av[4], bv[4];
#pragma unroll
      for (int mi = 0; mi < 4; ++mi) {
        const int row = wr * 64 + mi * 16 + fr;
        const int ch = (kk * 4 + fq) ^ (fr & 7);
        av[mi] = *reinterpret_cast<const bf16x8*>((const char*)lsA + row * 128 + ch * 16);
      }
#pragma unroll
      for (int ni = 0; ni < 4; ++ni) {
        const int row = wc * 64 + ni * 16 + fr;
        const int ch = (kk * 4 + fq) ^ (fr & 7);
        bv[ni] = *reinterpret_cast<const bf16x8*>((const char*)lsB + row * 128 + ch * 16);
      }
#pragma unroll
      for (int mi = 0; mi < 4; ++mi)
#pragma unroll
        for (int ni = 0; ni < 4; ++ni)
          acc[mi][ni] = __builtin_amdgcn_mfma_f32_16x16x32_bf16(av[mi], bv[ni], acc[mi][ni], 0, 0, 0);
    }
    __syncthreads();
  }

#pragma unroll
  for (int mi = 0; mi < 4; ++mi) {
#pragma unroll
    for (int ni = 0; ni < 4; ++ni) {
      const int col = bn0 + wc * 64 + ni * 16 + fr;
      const int row0 = bm0 + wr * 64 + mi * 16 + fq * 4;
      if constexpr (MODE == 0) {
        float* O = (float*)outp;
        const float b = ((const float*)extra)[col];
#pragma unroll
        for (int j = 0; j < 4; ++j)
          O[(long)(row0 + j) * N + col] = acc[mi][ni][j] + b;
      } else if constexpr (MODE == 1) {
        float* O = (float*)outp;
#pragma unroll
        for (int j = 0; j < 4; ++j)
          O[(long)(row0 + j) * N + col] = acc[mi][ni][j] + ((const float*)extra)[(long)(row0 + j) * N + col];
      } else if constexpr (MODE == 2) {
        unsigned short* O = (unsigned short*)outp;
#pragma unroll
        for (int j = 0; j < 4; ++j)
          O[(long)(row0 + j) * N + col] = f2bf(acc[mi][ni][j]);
      } else if constexpr (MODE == 3) {
        unsigned short* O = (unsigned short*)outp;
        const float b = ((const float*)extra)[col];
#pragma unroll
        for (int j = 0; j < 4; ++j)
          O[(long)(row0 + j) * N + col] = f2bf(acc[mi][ni][j] + b);
      } else {  // MODE 4: fused SwiGLU
        unsigned short* O = (unsigned short*)outp;
        const unsigned short* Abuf = (const unsigned short*)extra;
#pragma unroll
        for (int j = 0; j < 4; ++j) {
          const long idx = (long)(row0 + j) * N + col;
          const float a = bf2f(Abuf[idx]);
          O[idx] = f2bf(acc[mi][ni][j] * a / (1.f + __expf(-a)));
        }
      }
    }
  }
}

// ---------------- RoPE + QKV split (Q pre-scaled by 1/sqrt(D)) -------------
// mixed is bf16 [s][4608]. qr: [h][s][d]  kr: [kh][s][d]  vr: [kh][d][s]
// (V transposed so attention can stage it with global_load_lds)
__global__ __launch_bounds__(256)
void rope_split(const unsigned short* __restrict__ mixed, const float* __restrict__ cache,
                unsigned short* __restrict__ qr, unsigned short* __restrict__ kr,
                unsigned short* __restrict__ vr) {
  const int s = blockIdx.x, t = threadIdx.x;
  const unsigned short* row = mixed + (long)s * 4608;
  const float* c = cache + (long)s * 64;
  const float SCALE = 0.08838834764831845f;  // 1/sqrt(128)
  // Q rotated dims (32 heads x 32 pairs)
  for (int p = t; p < 1024; p += 256) {
    const int hq = p >> 5, pr = p & 31;
    const float x0 = bf2f(row[hq * 128 + 2 * pr]), x1 = bf2f(row[hq * 128 + 2 * pr + 1]);
    const float c0 = c[2 * pr], c1 = c[2 * pr + 1];
    unsigned short* qp = qr + ((long)hq * 2048 + s) * 128;
    qp[2 * pr] = f2bf((x0 * c0 - x1 * c1) * SCALE);
    qp[2 * pr + 1] = f2bf((x1 * c0 + x0 * c1) * SCALE);
  }
  // Q passthrough dims (32 heads x 64)
  for (int i = t; i < 2048; i += 256) {
    const int hq = i >> 6, d = 64 + (i & 63);
    qr[((long)hq * 2048 + s) * 128 + d] = f2bf(bf2f(row[hq * 128 + d]) * SCALE);
  }
  // K rotated (2 heads x 32 pairs)
  for (int p = t; p < 64; p += 256) {
    const int kh = p >> 5, pr = p & 31;
    const float x0 = bf2f(row[4096 + kh * 128 + 2 * pr]);
    const float x1 = bf2f(row[4096 + kh * 128 + 2 * pr + 1]);
    const float c0 = c[2 * pr], c1 = c[2 * pr + 1];
    unsigned short* kp = kr + ((long)kh * 2048 + s) * 128;
    kp[2 * pr] = f2bf(x0 * c0 - x1 * c1);
    kp[2 * pr + 1] = f2bf(x1 * c0 + x0 * c1);
  }
  // K passthrough (2 x 64)
  for (int i = t; i < 128; i += 256) {
    const int kh = i >> 6, d = 64 + (i & 63);
    kr[((long)kh * 2048 + s) * 128 + d] = row[4096 + kh * 128 + d];
  }
  // V transposed: vr[kh][d][s]  (2B scatter; 1MB region -> L2 absorbs)
  for (int i = t; i < 256; i += 256) {
    const int kh = i >> 7, d = i & 127;
    vr[((long)kh * 128 + d) * 2048 + s] = row[4352 + kh * 128 + d];
  }
}

// ---------------- causal flash attention, GQA 16:1, D=128 ------------------
// block = 4 waves, 64 q-rows (16/wave); KV tiles of 64.
// Kl: [kv][d] 16B chunks swizzled ^(kv&7);  Vt: [d][kv] chunks swizzled ^(d&7)
// Pl pitch 68 shorts: write banks (8(fq+ni)+2j+fr/2)%32 — conflict-free;
// read lands at the 8-cycle wave64 b128 structural minimum.
// Heavy-first: qb = 31 - (blockIdx.x&31) so 32-tile blocks dispatch before
// 1-tile blocks (LPT ordering shrinks the residency tail at ~3 blocks/CU).
__global__ __launch_bounds__(256)
void attn_fwd(const unsigned short* __restrict__ Q,
              const unsigned short* __restrict__ Kv,
              const unsigned short* __restrict__ Vt_g,
              unsigned short* __restrict__ ctx) {
  __shared__ unsigned short Kl[64 * 128];
  __shared__ unsigned short Vt[128 * 64];
  __shared__ unsigned short Pl[4][16 * 68];
  const int t = threadIdx.x, l = t & 63, w = t >> 6;
  const int fr = l & 15, fq = l >> 4;
  const int h = blockIdx.x >> 5, qb = 31 - (blockIdx.x & 31);
  const int kvh = h >> 4;
  const int q0 = qb * 64;

  bf16x8 qa[4];
  {
    const unsigned short* qp = Q + ((long)h * 2048 + q0 + w * 16 + fr) * 128;
#pragma unroll
    for (int cc = 0; cc < 4; ++cc)
      qa[cc] = *reinterpret_cast<const bf16x8*>(qp + cc * 32 + fq * 8);
  }
  float m[4], lsum[4];
  f32x4 o[8] = {};
#pragma unroll
  for (int j = 0; j < 4; ++j) { m[j] = -1e30f; lsum[j] = 0.f; }

  for (int tile = 0; tile <= qb; ++tile) {
    const int kv0 = tile * 64;
    // stage K: rows=kv (256B each); wave stages 4 rows per i
#pragma unroll
    for (int i = 0; i < 4; ++i) {
      const int kv = i * 16 + w * 4 + fq;
      glds16(Kv + ((long)kvh * 2048 + kv0 + kv) * 128 + (fr ^ (kv & 7)) * 8,
             (char*)Kl + i * 4096 + w * 1024);
    }
    // stage V from vr[kvh][d][s]: rows=d (128B each); 8 rows/wave/i
#pragma unroll
    for (int i = 0; i < 4; ++i) {
      const int d = i * 32 + w * 8 + (l >> 3);
      glds16(Vt_g + ((long)kvh * 128 + d) * 2048 + kv0 + (((l & 7) ^ (l >> 3)) * 8),
             (char*)Vt + i * 4096 + w * 1024);
    }
    __syncthreads();

    // S = Q K^T
    f32x4 sc4[4] = {};
#pragma unroll
    for (int ni = 0; ni < 4; ++ni) {
      const int kvr = ni * 16 + fr;
      const int swz = kvr & 7;
#pragma unroll
      for (int cc = 0; cc < 4; ++cc) {
        bf16x8 kb = *reinterpret_cast<const bf16x8*>((const char*)Kl + kvr * 256 + ((cc * 4 + fq) ^ swz) * 16);
        sc4[ni] = __builtin_amdgcn_mfma_f32_16x16x32_bf16(qa[cc], kb, sc4[ni], 0, 0, 0);
      }
    }
    if (tile == qb) {  // diagonal tile: causal mask
#pragma unroll
      for (int ni = 0; ni < 4; ++ni)
#pragma unroll
        for (int j = 0; j < 4; ++j)
          if (ni * 16 + fr > w * 16 + fq * 4 + j) sc4[ni][j] = -1e30f;
    }
    // online softmax (rows live across 16-lane fr groups)
#pragma unroll
    for (int j = 0; j < 4; ++j) {
      float v = fmaxf(fmaxf(sc4[0][j], sc4[1][j]), fmaxf(sc4[2][j], sc4[3][j]));
#pragma unroll
      for (int off = 1; off < 16; off <<= 1) v = fmaxf(v, __shfl_xor(v, off));
      const float mn = fmaxf(m[j], v);
      const float sc = __expf(m[j] - mn);
      m[j] = mn;
      float r = 0.f;
#pragma unroll
      for (int ni = 0; ni < 4; ++ni) {
        const float p = __expf(sc4[ni][j] - mn);
        sc4[ni][j] = p;
        r += p;
      }
#pragma unroll
      for (int off = 1; off < 16; off <<= 1) r += __shfl_xor(r, off);
      lsum[j] = lsum[j] * sc + r;
#pragma unroll
      for (int d = 0; d < 8; ++d) o[d][j] *= sc;
    }
    // P -> LDS (per-wave), then PV
#pragma unroll
    for (int ni = 0; ni < 4; ++ni)
#pragma unroll
      for (int j = 0; j < 4; ++j)
        Pl[w][(fq * 4 + j) * 68 + ni * 16 + fr] = f2bf(sc4[ni][j]);
#pragma unroll
    for (int kk = 0; kk < 2; ++kk) {
      bf16x8 pa = *reinterpret_cast<const bf16x8*>((const char*)&Pl[w][0] + fr * 136 + kk * 64 + fq * 16);
#pragma unroll
      for (int dj = 0; dj < 8; ++dj) {
        const int d = dj * 16 + fr;
        bf16x8 vb = *reinterpret_cast<const bf16x8*>((const char*)Vt + d * 128 + (((kk * 4 + fq) ^ (d & 7)) << 4));
        o[dj] = __builtin_amdgcn_mfma_f32_16x16x32_bf16(pa, vb, o[dj], 0, 0, 0);
      }
    }
    __syncthreads();
  }

#pragma unroll
  for (int j = 0; j < 4; ++j) {
    const float inv = 1.f / lsum[j];
    const long srow = q0 + w * 16 + fq * 4 + j;
#pragma unroll
    for (int dj = 0; dj < 8; ++dj)
      ctx[srow * 4096 + h * 128 + dj * 16 + fr] = f2bf(o[dj][j] * inv);
  }
}

// ---------------- host orchestration ---------------------------------------
// ws layout (liveness-aliased, peak ~262MB):
//  wbuf  [112.2MB] bf16 weight slot (qkv 37.7 / dense 33.5 / h4h-half 112 / 4hh 112)
//  lnin  [32MB]    fp32 residual, live to the end
//  lnslot[16MB]    ln1 (dead after QKV gemm) then ln2
//  slotA [56.1MB]  mixed bf16 (dead after rope) -> interA -> act (in-place MODE 4)
//  slotB [56.1MB]  qr+kr+vr+ctx (dead after dense gemm)
extern "C" void kernel_launch(void* const* d_in, const int* in_sizes, int n_in,
                              void* d_out, int out_size, void* d_ws, size_t ws_size,
                              hipStream_t stream) {
  (void)in_sizes; (void)n_in; (void)out_size; (void)ws_size;
  const float* hidden = (const float*)d_in[0];
  const float* rope_c = (const float*)d_in[1];
  const float* w_ln1 = (const float*)d_in[2];
  const float* w_qkv = (const float*)d_in[3];
  const float* b_qkv = (const float*)d_in[4];
  const float* w_dense = (const float*)d_in[5];
  const float* w_ln2 = (const float*)d_in[6];
  const float* w_h4h = (const float*)d_in[7];
  const float* w_4hh = (const float*)d_in[8];
  float* out = (float*)d_out;

  char* ws = (char*)d_ws;
  const size_t MB = 1024 * 1024;
  unsigned short* wbuf = (unsigned short*)ws;                        // 112,197,632
  float* lnin = (float*)(ws + 112197632);                            // 33,554,432
  char* lnslot = ws + 112197632 + 33554432;                          // 16,777,216
  char* slotA = lnslot + 16777216;                                   // 56,098,816
  char* slotB = slotA + 56098816;                                    // 56,098,816
  unsigned short* ln1 = (unsigned short*)lnslot;
  unsigned short* ln2 = ln1;
  unsigned short* mixed = (unsigned short*)slotA;  // bf16
  unsigned short* interA = (unsigned short*)slotA;
  unsigned short* act = interA;  // in-place fused SwiGLU (MODE 4)
  unsigned short* qr = (unsigned short*)slotB;
  unsigned short* kr = (unsigned short*)(slotB + 16 * MB);
  unsigned short* vr = (unsigned short*)(slotB + 17 * MB);
  unsigned short* ctx = (unsigned short*)(slotB + 18 * MB);

  const dim3 blk(256);
  cvt_bf16<<<2048, blk, 0, stream>>>(w_qkv, wbuf, (long)4608 * 4096 / 8);
  rmsnorm_k<<<2048, blk, 0, stream>>>(hidden, w_ln1, ln1);
  gemm_nt<3><<<dim3(16, 36), blk, 0, stream>>>(ln1, wbuf, mixed, b_qkv, 2048, 4608, 4096);
  rope_split<<<2048, blk, 0, stream>>>(mixed, rope_c, qr, kr, vr);
  attn_fwd<<<1024, blk, 0, stream>>>(qr, kr, vr, ctx);
  cvt_bf16<<<2048, blk, 0, stream>>>(w_dense, wbuf, (long)4096 * 4096 / 8);
  gemm_nt<1><<<dim3(16, 32), blk, 0, stream>>>(ctx, wbuf, lnin, hidden, 2048, 4096, 4096);
  rmsnorm_k<<<2048, blk, 0, stream>>>(lnin, w_ln2, ln2);
  // h->4h in two N-halves sharing wbuf; second half fuses SwiGLU (MODE 4)
  cvt_bf16<<<4096, blk, 0, stream>>>(w_h4h, wbuf, (long)13696 * 4096 / 8);
  gemm_nt<2><<<dim3(16, 107), blk, 0, stream>>>(ln2, wbuf, interA, nullptr, 2048, 13696, 4096);
  cvt_bf16<<<4096, blk, 0, stream>>>(w_h4h + (long)13696 * 4096, wbuf, (long)13696 * 4096 / 8);
  gemm_nt<4><<<dim3(16, 107), blk, 0, stream>>>(ln2, wbuf, act, interA, 2048, 13696, 4096);
  cvt_bf16<<<4096, blk, 0, stream>>>(w_4hh, wbuf, (long)4096 * 13696 / 8);
  gemm_nt<1><<<dim3(16, 32), blk, 0, stream>>>(act, wbuf, out, lnin, 2048, 4096, 13696);
}